// Round 7
// baseline (195.312 us; speedup 1.0000x reference)
//
#include <hip/hip_runtime.h>

// Problem constants (fixed by reference)
#define NPTS  8192
#define GXD   334
#define GYD   334
#define GZD   2
#define BATCH 2
#define HSIZE 16384
#define HMASK 16383
#define KADJ  50

#define GBLK  2048    // gather: one 64-lane wave per point, 4 waves/block
#define GTHR  256

__device__ __forceinline__ unsigned hashv(unsigned v) {
    unsigned h = v * 2654435761u;
    h ^= h >> 15;
    return h & HMASK;
}

// ECL-CC-style find with path halving. Parent values are always smaller
// same-component members (monotone chains); stale reads at worst cause a
// CAS retry in unite().
__device__ __forceinline__ int rep_find(int* parent, int v) {
    int curr = parent[v];
    if (curr != v) {
        int prev = v, next;
        while (curr > (next = parent[curr])) {
            parent[prev] = next;   // halving hint (benign race)
            prev = curr;
            curr = next;
        }
    }
    return curr;
}

__device__ __forceinline__ void unite(int* parent, int u, int v) {
    int ru = rep_find(parent, u);
    int rv = rep_find(parent, v);
    while (ru != rv) {
        if (ru < rv) { int t = ru; ru = rv; rv = t; }   // ru = larger
        int prev = atomicCAS(&parent[ru], ru, rv);
        if (prev == ru) return;
        ru = rep_find(parent, prev);
        rv = rep_find(parent, rv);
    }
}

// Phase 0: zero hash table + done counter; init union-find; precompute packed
// voxel coords per point. All independent work -> single kernel, no memset.
__global__ void k_init(const float* __restrict__ pts, const int* __restrict__ bidx,
                       int* hkey, float* hcnt, float* hsx, float* hsy, float* hsz,
                       int* hrep, int* parent, int* pvid, int* done) {
    int t = blockIdx.x * blockDim.x + threadIdx.x;   // 0..16383
    hkey[t] = -1;
    hcnt[t] = 0.0f;
    hsx[t]  = 0.0f;
    hsy[t]  = 0.0f;
    hsz[t]  = 0.0f;
    hrep[t] = 0;                                      // 0 = empty (enc NPTS-i >= 1)
    if (t == 0) *done = 0;
    if (t < NPTS) {
        parent[t] = t;
        // Mirror ref exactly: floor((p - PC_MIN)/VOXEL), clip after cast.
        float x = pts[3 * t + 0], y = pts[3 * t + 1], z = pts[3 * t + 2];
        int cx = (int)floorf((x - (-50.0f)) / 0.3f);
        int cy = (int)floorf((y - (-50.0f)) / 0.3f);
        int cz = (int)floorf((z - (-5.0f))  / 6.0f);
        cx = min(max(cx, 0), GXD - 1);
        cy = min(max(cy, 0), GYD - 1);
        cz = min(max(cz, 0), GZD - 1);
        int b = bidx[t];
        pvid[t] = cx | (cy << 9) | (cz << 18) | (b << 19);
    }
}

// Phase 1: hash-insert + accumulate voxel stats.
// rep encoding: atomicMax(NPTS-i) over zero-init -> decode NPTS-v = min index.
__global__ void k_accum(const float* __restrict__ pts, const int* __restrict__ pvid,
                        int* hkey, float* hcnt, float* hsx, float* hsy, float* hsz,
                        int* hrep) {
    int i = blockIdx.x * blockDim.x + threadIdx.x;
    if (i >= NPTS) return;
    int p  = pvid[i];
    int cx = p & 511, cy = (p >> 9) & 511, cz = (p >> 18) & 1, b = (p >> 19) & 1;
    int vid = ((b * GZD + cz) * GYD + cy) * GXD + cx;
    unsigned h = hashv((unsigned)vid);
    int slot;
    for (;;) {
        int prev = atomicCAS(&hkey[h], -1, vid);
        if (prev == -1 || prev == vid) { slot = (int)h; break; }
        h = (h + 1) & HMASK;
    }
    float x = pts[3 * i + 0], y = pts[3 * i + 1], z = pts[3 * i + 2];
    atomicAdd(&hcnt[slot], 1.0f);
    atomicAdd(&hsx[slot], x);
    atomicAdd(&hsy[slot], y);
    atomicAdd(&hsz[slot], z);
    atomicMax(&hrep[slot], NPTS - i);
    }

__device__ __forceinline__ int hlookup(const int* __restrict__ hkey, int vid) {
    unsigned h = hashv((unsigned)vid);
    for (;;) {
        int k = hkey[h];
        if (k == vid) return (int)h;
        if (k == -1)  return -1;
        h = (h + 1) & HMASK;
    }
}

// Phase 2: one wave per point; lane < 50 owns window cell (zz,dy,dx); passing
// lanes unite(point, neighbor-voxel rep). LAST block then writes all labels.
__global__ void __launch_bounds__(GTHR) k_gather_fused(
        const int* __restrict__ pvid,
        const int* __restrict__ hkey, const float* __restrict__ hcnt,
        const float* __restrict__ hsx, const float* __restrict__ hsy,
        const float* __restrict__ hsz, const int* __restrict__ hrep,
        int* parent, int* done, float* __restrict__ out) {
    int tid  = blockIdx.x * GTHR + threadIdx.x;
    int i    = tid >> 6;          // point index
    int lane = tid & 63;

    int p  = pvid[i];             // wave-uniform
    int cx = p & 511, cy = (p >> 9) & 511, cz = (p >> 18) & 1, b = (p >> 19) & 1;

    bool  occ = false;
    float ncn = 1.0f, nxc = 0.0f, nyc = 0.0f, nzc = 0.0f;
    int   nrep = 0;
    if (lane < KADJ) {
        int zz  = lane / 25;
        int rem = lane % 25;
        int dy  = rem / 5 - 2;
        int dx  = rem % 5 - 2;
        int ny = cy + dy, nx = cx + dx;
        if (ny >= 0 && ny < GYD && nx >= 0 && nx < GXD) {
            int nvid = ((b * GZD + zz) * GYD + ny) * GXD + nx;
            int s = hlookup(hkey, nvid);
            if (s >= 0) {
                occ  = true;
                ncn  = fmaxf(hcnt[s], 1.0f);    // ref: sums / maximum(cnt,1)
                nxc  = hsx[s] / ncn;
                nyc  = hsy[s] / ncn;
                nzc  = hsz[s] / ncn;
                nrep = NPTS - hrep[s];          // min point index of that voxel
            }
        }
    }

    // own voxel center broadcast from the (dx=0,dy=0,zz=cz) lane
    int lane_own = cz * 25 + 12;
    float cxf = __shfl(nxc, lane_own);
    float cyf = __shfl(nyc, lane_own);
    float czf = __shfl(nzc, lane_own);

    if (occ) {
        float ddx = cxf - nxc;
        float ddy = cyf - nyc;
        // separate roundings like ref (no FMA contraction)
        float sq = __fadd_rn(__fmul_rn(ddx, ddx), __fmul_rn(ddy, ddy));
        if (sqrtf(sq) < 0.6f && nrep != i)
            unite(parent, i, nrep);
    }

    if (lane == 0) {
        // float32 outputs: cluster_inds interleaved [b,c], valid, cpp
        out[2 * i]                = (float)b;
        out[2 * NPTS + i]         = 1.0f;       // cnt >= MIN_POINTS=1 always
        out[3 * NPTS + 3 * i + 0] = cxf;
        out[3 * NPTS + 3 * i + 1] = cyf;
        out[3 * NPTS + 3 * i + 2] = czf;
    }

    // ---- last-block writes labels (fully parallel root chase) ----
    __shared__ int isLast;
    __threadfence();                            // publish unions/outputs (release)
    __syncthreads();
    if (threadIdx.x == 0)
        isLast = (atomicAdd(done, 1) == GBLK - 1);
    __syncthreads();
    if (!isLast) return;
    __threadfence();                            // acquire all blocks' stores

    for (int j = threadIdx.x; j < NPTS; j += GTHR) {
        int r = __hip_atomic_load(&parent[j], __ATOMIC_RELAXED, __HIP_MEMORY_SCOPE_AGENT);
        for (;;) {
            int rr = __hip_atomic_load(&parent[r], __ATOMIC_RELAXED, __HIP_MEMORY_SCOPE_AGENT);
            if (rr == r) break;
            r = rr;
        }
        out[2 * j + 1] = (float)r;              // root == component min == ref label
    }
}

extern "C" void kernel_launch(void* const* d_in, const int* in_sizes, int n_in,
                              void* d_out, int out_size, void* d_ws, size_t ws_size,
                              hipStream_t stream) {
    const float* pts  = (const float*)d_in[0];
    const int*   bidx = (const int*)d_in[1];
    float* out = (float*)d_out;

    char* w = (char*)d_ws;
    int*   hkey   = (int*)  (w + 0);
    float* hcnt   = (float*)(w + 65536);
    float* hsx    = (float*)(w + 131072);
    float* hsy    = (float*)(w + 196608);
    float* hsz    = (float*)(w + 262144);
    int*   hrep   = (int*)  (w + 327680);
    int*   parent = (int*)  (w + 393216);   // 8192 ints
    int*   pvid   = (int*)  (w + 425984);   // 8192 ints
    int*   done   = (int*)  (w + 458752);   // 1 int   (total ws use ~459 KB)

    hipLaunchKernelGGL(k_init,  dim3(HSIZE / 256), dim3(256), 0, stream,
                       pts, bidx, hkey, hcnt, hsx, hsy, hsz, hrep, parent, pvid, done);
    hipLaunchKernelGGL(k_accum, dim3(NPTS / 256),  dim3(256), 0, stream,
                       pts, pvid, hkey, hcnt, hsx, hsy, hsz, hrep);
    hipLaunchKernelGGL(k_gather_fused, dim3(GBLK), dim3(GTHR), 0, stream,
                       pvid, hkey, hcnt, hsx, hsy, hsz, hrep, parent, done, out);
}

// Round 8
// 66.146 us; speedup vs baseline: 2.9527x; 2.9527x over previous
//
#include <hip/hip_runtime.h>

// Problem constants (fixed by reference)
#define NPTS  8192
#define GXD   334
#define GYD   334
#define GZD   2
#define BATCH 2
#define HSIZE 16384
#define HMASK 16383
#define KADJ  50

#define GBLK  2048    // gather: one 64-lane wave per point, 4 waves/block
#define GTHR  256

__device__ __forceinline__ unsigned hashv(unsigned v) {
    unsigned h = v * 2654435761u;
    h ^= h >> 15;
    return h & HMASK;
}

// ECL-CC-style find with path halving. Parent values are always smaller
// same-component members (monotone chains); stale reads at worst cause a
// CAS retry in unite(). Halving stores are hints; stale hints are older
// valid ancestors -> benign.
__device__ __forceinline__ int rep_find(int* parent, int v) {
    int curr = parent[v];
    if (curr != v) {
        int prev = v, next;
        while (curr > (next = parent[curr])) {
            parent[prev] = next;   // halving hint (benign race)
            prev = curr;
            curr = next;
        }
    }
    return curr;
}

__device__ __forceinline__ void unite(int* parent, int u, int v) {
    int ru = rep_find(parent, u);
    int rv = rep_find(parent, v);
    while (ru != rv) {
        if (ru < rv) { int t = ru; ru = rv; rv = t; }   // ru = larger
        int prev = atomicCAS(&parent[ru], ru, rv);      // device-scope RMW
        if (prev == ru) return;
        ru = rep_find(parent, prev);
        rv = rep_find(parent, rv);
    }
}

// Phase 0: zero hash table + done counter; init union-find; precompute packed
// voxel coords per point. All independent work -> one kernel, no memsets.
__global__ void k_init(const float* __restrict__ pts, const int* __restrict__ bidx,
                       int* hkey, float* hcnt, float* hsx, float* hsy, float* hsz,
                       int* hrep, int* parent, int* pvid, int* done) {
    int t = blockIdx.x * blockDim.x + threadIdx.x;   // 0..16383
    hkey[t] = -1;
    hcnt[t] = 0.0f;
    hsx[t]  = 0.0f;
    hsy[t]  = 0.0f;
    hsz[t]  = 0.0f;
    hrep[t] = 0;                                      // 0 = empty (enc NPTS-i >= 1)
    if (t == 0) *done = 0;
    if (t < NPTS) {
        parent[t] = t;
        // Mirror ref exactly: floor((p - PC_MIN)/VOXEL), clip after cast.
        float x = pts[3 * t + 0], y = pts[3 * t + 1], z = pts[3 * t + 2];
        int cx = (int)floorf((x - (-50.0f)) / 0.3f);
        int cy = (int)floorf((y - (-50.0f)) / 0.3f);
        int cz = (int)floorf((z - (-5.0f))  / 6.0f);
        cx = min(max(cx, 0), GXD - 1);
        cy = min(max(cy, 0), GYD - 1);
        cz = min(max(cz, 0), GZD - 1);
        int b = bidx[t];
        pvid[t] = cx | (cy << 9) | (cz << 18) | (b << 19);
    }
}

// Phase 1: hash-insert + accumulate voxel stats.
// rep encoding: atomicMax(NPTS-i) over zero-init -> decode NPTS-v = min index.
__global__ void k_accum(const float* __restrict__ pts, const int* __restrict__ pvid,
                        int* hkey, float* hcnt, float* hsx, float* hsy, float* hsz,
                        int* hrep) {
    int i = blockIdx.x * blockDim.x + threadIdx.x;
    if (i >= NPTS) return;
    int p  = pvid[i];
    int cx = p & 511, cy = (p >> 9) & 511, cz = (p >> 18) & 1, b = (p >> 19) & 1;
    int vid = ((b * GZD + cz) * GYD + cy) * GXD + cx;
    unsigned h = hashv((unsigned)vid);
    int slot;
    for (;;) {
        int prev = atomicCAS(&hkey[h], -1, vid);
        if (prev == -1 || prev == vid) { slot = (int)h; break; }
        h = (h + 1) & HMASK;
    }
    float x = pts[3 * i + 0], y = pts[3 * i + 1], z = pts[3 * i + 2];
    atomicAdd(&hcnt[slot], 1.0f);
    atomicAdd(&hsx[slot], x);
    atomicAdd(&hsy[slot], y);
    atomicAdd(&hsz[slot], z);
    atomicMax(&hrep[slot], NPTS - i);
}

__device__ __forceinline__ int hlookup(const int* __restrict__ hkey, int vid) {
    unsigned h = hashv((unsigned)vid);
    for (;;) {
        int k = hkey[h];
        if (k == vid) return (int)h;
        if (k == -1)  return -1;
        h = (h + 1) & HMASK;
    }
}

// Phase 2: one wave per point; lane < 50 owns window cell (zz,dy,dx); passing
// lanes unite(point, neighbor-voxel rep). LAST block then writes all labels.
// NO __threadfence (round-7 lesson: device fences in wide launches cost ~150us
// on MI355X). Release/acquire is carried by atomic RMWs: __syncthreads drains
// vmcnt(0) so unions are performed at the coherence point before atomicAdd(done);
// the last block chases roots with agent-scope atomic loads (L1-bypassing).
__global__ void __launch_bounds__(GTHR) k_gather_fused(
        const int* __restrict__ pvid,
        const int* __restrict__ hkey, const float* __restrict__ hcnt,
        const float* __restrict__ hsx, const float* __restrict__ hsy,
        const float* __restrict__ hsz, const int* __restrict__ hrep,
        int* parent, int* done, float* __restrict__ out) {
    int tid  = blockIdx.x * GTHR + threadIdx.x;
    int i    = tid >> 6;          // point index
    int lane = tid & 63;

    int p  = pvid[i];             // wave-uniform
    int cx = p & 511, cy = (p >> 9) & 511, cz = (p >> 18) & 1, b = (p >> 19) & 1;

    bool  occ = false;
    float ncn = 1.0f, nxc = 0.0f, nyc = 0.0f, nzc = 0.0f;
    int   nrep = 0;
    if (lane < KADJ) {
        int zz  = lane / 25;
        int rem = lane % 25;
        int dy  = rem / 5 - 2;
        int dx  = rem % 5 - 2;
        int ny = cy + dy, nx = cx + dx;
        if (ny >= 0 && ny < GYD && nx >= 0 && nx < GXD) {
            int nvid = ((b * GZD + zz) * GYD + ny) * GXD + nx;
            int s = hlookup(hkey, nvid);
            if (s >= 0) {
                occ  = true;
                ncn  = fmaxf(hcnt[s], 1.0f);    // ref: sums / maximum(cnt,1)
                nxc  = hsx[s] / ncn;
                nyc  = hsy[s] / ncn;
                nzc  = hsz[s] / ncn;
                nrep = NPTS - hrep[s];          // min point index of that voxel
            }
        }
    }

    // own voxel center broadcast from the (dx=0,dy=0,zz=cz) lane
    int lane_own = cz * 25 + 12;
    float cxf = __shfl(nxc, lane_own);
    float cyf = __shfl(nyc, lane_own);
    float czf = __shfl(nzc, lane_own);

    if (occ) {
        float ddx = cxf - nxc;
        float ddy = cyf - nyc;
        // separate roundings like ref (no FMA contraction)
        float sq = __fadd_rn(__fmul_rn(ddx, ddx), __fmul_rn(ddy, ddy));
        if (sqrtf(sq) < 0.6f && nrep != i)
            unite(parent, i, nrep);
    }

    if (lane == 0) {
        // float32 outputs: cluster_inds interleaved [b,c], valid, cpp
        out[2 * i]                = (float)b;
        out[2 * NPTS + i]         = 1.0f;       // cnt >= MIN_POINTS=1 always
        out[3 * NPTS + 3 * i + 0] = cxf;
        out[3 * NPTS + 3 * i + 1] = cyf;
        out[3 * NPTS + 3 * i + 2] = czf;
    }

    // ---- fence-free last-block handshake ----
    __shared__ int isLast;
    __syncthreads();                            // drains vmcnt(0): unions performed
    if (threadIdx.x == 0)
        isLast = (atomicAdd(done, 1) == GBLK - 1);
    __syncthreads();
    if (!isLast) return;

    // Root chase: all parent mutations were device-scope atomic RMWs (performed
    // at the coherence point); agent-scope atomic loads bypass stale L1/L2.
    for (int j = threadIdx.x; j < NPTS; j += GTHR) {
        int r = __hip_atomic_load(&parent[j], __ATOMIC_RELAXED, __HIP_MEMORY_SCOPE_AGENT);
        for (;;) {
            int rr = __hip_atomic_load(&parent[r], __ATOMIC_RELAXED, __HIP_MEMORY_SCOPE_AGENT);
            if (rr == r) break;
            r = rr;
        }
        out[2 * j + 1] = (float)r;              // root == component min == ref label
    }
}

extern "C" void kernel_launch(void* const* d_in, const int* in_sizes, int n_in,
                              void* d_out, int out_size, void* d_ws, size_t ws_size,
                              hipStream_t stream) {
    const float* pts  = (const float*)d_in[0];
    const int*   bidx = (const int*)d_in[1];
    float* out = (float*)d_out;

    char* w = (char*)d_ws;
    int*   hkey   = (int*)  (w + 0);
    float* hcnt   = (float*)(w + 65536);
    float* hsx    = (float*)(w + 131072);
    float* hsy    = (float*)(w + 196608);
    float* hsz    = (float*)(w + 262144);
    int*   hrep   = (int*)  (w + 327680);
    int*   parent = (int*)  (w + 393216);   // 8192 ints
    int*   pvid   = (int*)  (w + 425984);   // 8192 ints
    int*   done   = (int*)  (w + 458752);   // 1 int   (total ws use ~459 KB)

    hipLaunchKernelGGL(k_init,  dim3(HSIZE / 256), dim3(256), 0, stream,
                       pts, bidx, hkey, hcnt, hsx, hsy, hsz, hrep, parent, pvid, done);
    hipLaunchKernelGGL(k_accum, dim3(NPTS / 256),  dim3(256), 0, stream,
                       pts, pvid, hkey, hcnt, hsx, hsy, hsz, hrep);
    hipLaunchKernelGGL(k_gather_fused, dim3(GBLK), dim3(GTHR), 0, stream,
                       pvid, hkey, hcnt, hsx, hsy, hsz, hrep, parent, done, out);
}

// Round 9
// 36.200 us; speedup vs baseline: 5.3953x; 1.8272x over previous
//
#include <hip/hip_runtime.h>

// Problem constants (fixed by reference)
#define NPTS  8192
#define GXD   334
#define GYD   334
#define GZD   2
#define BATCH 2
#define HSIZE 16384
#define HMASK 16383
#define KADJ  50

#define GBLK  2048    // gather: one 64-lane wave per point, 4 waves/block
#define GTHR  256

__device__ __forceinline__ unsigned hashv(unsigned v) {
    unsigned h = v * 2654435761u;
    h ^= h >> 15;
    return h & HMASK;
}

// ECL-CC-style find with path halving. Parent values are always smaller
// same-component members (monotone chains); stale reads at worst cause a
// CAS retry in unite(). Halving stores are hints; stale hints are older
// valid ancestors -> benign.
__device__ __forceinline__ int rep_find(int* parent, int v) {
    int curr = parent[v];
    if (curr != v) {
        int prev = v, next;
        while (curr > (next = parent[curr])) {
            parent[prev] = next;   // halving hint (benign race)
            prev = curr;
            curr = next;
        }
    }
    return curr;
}

__device__ __forceinline__ void unite(int* parent, int u, int v) {
    int ru = rep_find(parent, u);
    int rv = rep_find(parent, v);
    while (ru != rv) {
        if (ru < rv) { int t = ru; ru = rv; rv = t; }   // ru = larger
        int prev = atomicCAS(&parent[ru], ru, rv);      // device-scope RMW
        if (prev == ru) return;
        ru = rep_find(parent, prev);
        rv = rep_find(parent, rv);
    }
}

// Phase 0: zero hash table; init union-find; precompute packed voxel coords.
// All independent work -> one kernel, no memsets, no fences.
__global__ void k_init(const float* __restrict__ pts, const int* __restrict__ bidx,
                       int* hkey, float* hcnt, float* hsx, float* hsy, float* hsz,
                       int* hrep, int* parent, int* pvid) {
    int t = blockIdx.x * blockDim.x + threadIdx.x;   // 0..16383
    hkey[t] = -1;
    hcnt[t] = 0.0f;
    hsx[t]  = 0.0f;
    hsy[t]  = 0.0f;
    hsz[t]  = 0.0f;
    hrep[t] = 0;                                      // 0 = empty (enc NPTS-i >= 1)
    if (t < NPTS) {
        parent[t] = t;
        // Mirror ref exactly: floor((p - PC_MIN)/VOXEL), clip after cast.
        float x = pts[3 * t + 0], y = pts[3 * t + 1], z = pts[3 * t + 2];
        int cx = (int)floorf((x - (-50.0f)) / 0.3f);
        int cy = (int)floorf((y - (-50.0f)) / 0.3f);
        int cz = (int)floorf((z - (-5.0f))  / 6.0f);
        cx = min(max(cx, 0), GXD - 1);
        cy = min(max(cy, 0), GYD - 1);
        cz = min(max(cz, 0), GZD - 1);
        int b = bidx[t];
        pvid[t] = cx | (cy << 9) | (cz << 18) | (b << 19);
    }
}

// Phase 1: hash-insert + accumulate voxel stats.
// rep encoding: atomicMax(NPTS-i) over zero-init -> decode NPTS-v = min index.
__global__ void k_accum(const float* __restrict__ pts, const int* __restrict__ pvid,
                        int* hkey, float* hcnt, float* hsx, float* hsy, float* hsz,
                        int* hrep) {
    int i = blockIdx.x * blockDim.x + threadIdx.x;
    if (i >= NPTS) return;
    int p  = pvid[i];
    int cx = p & 511, cy = (p >> 9) & 511, cz = (p >> 18) & 1, b = (p >> 19) & 1;
    int vid = ((b * GZD + cz) * GYD + cy) * GXD + cx;
    unsigned h = hashv((unsigned)vid);
    int slot;
    for (;;) {
        int prev = atomicCAS(&hkey[h], -1, vid);
        if (prev == -1 || prev == vid) { slot = (int)h; break; }
        h = (h + 1) & HMASK;
    }
    float x = pts[3 * i + 0], y = pts[3 * i + 1], z = pts[3 * i + 2];
    atomicAdd(&hcnt[slot], 1.0f);
    atomicAdd(&hsx[slot], x);
    atomicAdd(&hsy[slot], y);
    atomicAdd(&hsz[slot], z);
    atomicMax(&hrep[slot], NPTS - i);
}

__device__ __forceinline__ int hlookup(const int* __restrict__ hkey, int vid) {
    unsigned h = hashv((unsigned)vid);
    for (;;) {
        int k = hkey[h];
        if (k == vid) return (int)h;
        if (k == -1)  return -1;
        h = (h + 1) & HMASK;
    }
}

// Phase 2: one wave per point; lane < 50 owns window cell (zz,dy,dx); passing
// lanes unite(point, neighbor-voxel rep). No tail, no handshake, no fence —
// the kernel boundary is the cross-XCD release (round-7/8 lesson: in-kernel
// __threadfence ~150us, fused single-block tail ~+20us; a dispatch is ~3.5us).
__global__ void __launch_bounds__(GTHR) k_gather(
        const int* __restrict__ pvid,
        const int* __restrict__ hkey, const float* __restrict__ hcnt,
        const float* __restrict__ hsx, const float* __restrict__ hsy,
        const float* __restrict__ hsz, const int* __restrict__ hrep,
        int* parent, float* __restrict__ out) {
    int tid  = blockIdx.x * GTHR + threadIdx.x;
    int i    = tid >> 6;          // point index
    int lane = tid & 63;

    int p  = pvid[i];             // wave-uniform
    int cx = p & 511, cy = (p >> 9) & 511, cz = (p >> 18) & 1, b = (p >> 19) & 1;

    bool  occ = false;
    float ncn = 1.0f, nxc = 0.0f, nyc = 0.0f, nzc = 0.0f;
    int   nrep = 0;
    if (lane < KADJ) {
        int zz  = lane / 25;
        int rem = lane % 25;
        int dy  = rem / 5 - 2;
        int dx  = rem % 5 - 2;
        int ny = cy + dy, nx = cx + dx;
        if (ny >= 0 && ny < GYD && nx >= 0 && nx < GXD) {
            int nvid = ((b * GZD + zz) * GYD + ny) * GXD + nx;
            int s = hlookup(hkey, nvid);
            if (s >= 0) {
                occ  = true;
                ncn  = fmaxf(hcnt[s], 1.0f);    // ref: sums / maximum(cnt,1)
                nxc  = hsx[s] / ncn;
                nyc  = hsy[s] / ncn;
                nzc  = hsz[s] / ncn;
                nrep = NPTS - hrep[s];          // min point index of that voxel
            }
        }
    }

    // own voxel center broadcast from the (dx=0,dy=0,zz=cz) lane
    int lane_own = cz * 25 + 12;
    float cxf = __shfl(nxc, lane_own);
    float cyf = __shfl(nyc, lane_own);
    float czf = __shfl(nzc, lane_own);

    if (occ) {
        float ddx = cxf - nxc;
        float ddy = cyf - nyc;
        // separate roundings like ref (no FMA contraction)
        float sq = __fadd_rn(__fmul_rn(ddx, ddx), __fmul_rn(ddy, ddy));
        if (sqrtf(sq) < 0.6f && nrep != i)
            unite(parent, i, nrep);
    }

    if (lane == 0) {
        // float32 outputs: cluster_inds interleaved [b,c], valid, cpp
        out[2 * i]                = (float)b;
        out[2 * NPTS + i]         = 1.0f;       // cnt >= MIN_POINTS=1 always
        out[3 * NPTS + 3 * i + 0] = cxf;
        out[3 * NPTS + 3 * i + 1] = cyf;
        out[3 * NPTS + 3 * i + 2] = czf;
    }
}

// Phase 3: labels = component root (== min point index == ref label).
// Separate dispatch => all unions device-visible; plain cached loads suffice
// (dispatch-start acquire), parent is 32KB -> L2-resident chases.
__global__ void k_final(const int* __restrict__ parent, float* __restrict__ out) {
    int i = blockIdx.x * blockDim.x + threadIdx.x;
    if (i >= NPTS) return;
    int r = parent[i];
    for (;;) {
        int rr = parent[r];
        if (rr == r) break;
        r = rr;
    }
    out[2 * i + 1] = (float)r;
}

extern "C" void kernel_launch(void* const* d_in, const int* in_sizes, int n_in,
                              void* d_out, int out_size, void* d_ws, size_t ws_size,
                              hipStream_t stream) {
    const float* pts  = (const float*)d_in[0];
    const int*   bidx = (const int*)d_in[1];
    float* out = (float*)d_out;

    char* w = (char*)d_ws;
    int*   hkey   = (int*)  (w + 0);
    float* hcnt   = (float*)(w + 65536);
    float* hsx    = (float*)(w + 131072);
    float* hsy    = (float*)(w + 196608);
    float* hsz    = (float*)(w + 262144);
    int*   hrep   = (int*)  (w + 327680);
    int*   parent = (int*)  (w + 393216);   // 8192 ints
    int*   pvid   = (int*)  (w + 425984);   // 8192 ints (total ws use ~459 KB)

    hipLaunchKernelGGL(k_init,  dim3(HSIZE / 256), dim3(256), 0, stream,
                       pts, bidx, hkey, hcnt, hsx, hsy, hsz, hrep, parent, pvid);
    hipLaunchKernelGGL(k_accum, dim3(NPTS / 256),  dim3(256), 0, stream,
                       pts, pvid, hkey, hcnt, hsx, hsy, hsz, hrep);
    hipLaunchKernelGGL(k_gather, dim3(GBLK), dim3(GTHR), 0, stream,
                       pvid, hkey, hcnt, hsx, hsy, hsz, hrep, parent, out);
    hipLaunchKernelGGL(k_final, dim3(NPTS / 256), dim3(256), 0, stream,
                       parent, out);
}

// Round 10
// 25.148 us; speedup vs baseline: 7.7666x; 1.4395x over previous
//
#include <hip/hip_runtime.h>

// Problem constants (fixed by reference)
#define NPTS  8192
#define GXD   334
#define GYD   334
#define GZD   2
#define BATCH 2
#define NV    (BATCH * GZD * GYD * GXD)   // 446224 voxel cells
#define NVP   446464                       // padded to multiple of 256
#define KADJ  50

#define GBLK  2048    // gather: one 64-lane wave per point, 4 waves/block
#define GTHR  256

// ECL-CC-style find with path halving. Parent values are always smaller
// same-component members (monotone chains); stale reads at worst cause a
// CAS retry in unite(). Halving stores are hints; stale hints are older
// valid ancestors -> benign.
__device__ __forceinline__ int rep_find(int* parent, int v) {
    int curr = parent[v];
    if (curr != v) {
        int prev = v, next;
        while (curr > (next = parent[curr])) {
            parent[prev] = next;   // halving hint (benign race)
            prev = curr;
            curr = next;
        }
    }
    return curr;
}

__device__ __forceinline__ void unite(int* parent, int u, int v) {
    int ru = rep_find(parent, u);
    int rv = rep_find(parent, v);
    while (ru != rv) {
        if (ru < rv) { int t = ru; ru = rv; rv = t; }   // ru = larger
        int prev = atomicCAS(&parent[ru], ru, rv);      // device-scope RMW
        if (prev == ru) return;
        ru = rep_find(parent, prev);
        rv = rep_find(parent, rv);
    }
}

// Phase 1: dense direct-addressed voxel accumulate (round-6/9 A/B verdict:
// dense beats hash by ~11us — no dependent probe chains). Also initializes
// union-find and precomputes packed voxel coords for gather.
// rep encoding: atomicMax(NPTS-i) over zero-init -> decode NPTS-v = min index.
__global__ void k_accum(const float* __restrict__ pts, const int* __restrict__ bidx,
                        float* cnt, float* sx, float* sy, float* sz, int* rep,
                        int* parent, int* pvid) {
    int i = blockIdx.x * blockDim.x + threadIdx.x;
    if (i >= NPTS) return;
    parent[i] = i;
    float x = pts[3 * i + 0], y = pts[3 * i + 1], z = pts[3 * i + 2];
    // Mirror ref exactly: floor((p - PC_MIN)/VOXEL), clip after cast.
    int cx = (int)floorf((x - (-50.0f)) / 0.3f);
    int cy = (int)floorf((y - (-50.0f)) / 0.3f);
    int cz = (int)floorf((z - (-5.0f))  / 6.0f);
    cx = min(max(cx, 0), GXD - 1);
    cy = min(max(cy, 0), GYD - 1);
    cz = min(max(cz, 0), GZD - 1);
    int b = bidx[i];
    pvid[i] = cx | (cy << 9) | (cz << 18) | (b << 19);
    int vid = ((b * GZD + cz) * GYD + cy) * GXD + cx;
    atomicAdd(&cnt[vid], 1.0f);
    atomicAdd(&sx[vid], x);
    atomicAdd(&sy[vid], y);
    atomicAdd(&sz[vid], z);
    atomicMax(&rep[vid], NPTS - i);
}

// Phase 2: one wave per point; lane < 50 owns window cell (zz,dy,dx); passing
// lanes unite(point, neighbor-voxel rep). No tail, no handshake, no fence —
// the kernel boundary is the cross-XCD release (rounds 4/5/7/8: grid.sync
// ~100us, __threadfence ~150us, fused single-block tail +20us; dispatch ~3us).
__global__ void __launch_bounds__(GTHR) k_gather(
        const int* __restrict__ pvid,
        const float* __restrict__ cnt, const float* __restrict__ sx,
        const float* __restrict__ sy, const float* __restrict__ sz,
        const int* __restrict__ rep,
        int* parent, float* __restrict__ out) {
    int tid  = blockIdx.x * GTHR + threadIdx.x;
    int i    = tid >> 6;          // point index
    int lane = tid & 63;

    int p  = pvid[i];             // wave-uniform single load
    int cx = p & 511, cy = (p >> 9) & 511, cz = (p >> 18) & 1, b = (p >> 19) & 1;
    int vid = ((b * GZD + cz) * GYD + cy) * GXD + cx;

    bool  occ = false;
    float ncn = 1.0f, nxc = 0.0f, nyc = 0.0f;
    int   nrep = 0;
    if (lane < KADJ) {
        int zz  = lane / 25;
        int rem = lane % 25;
        int dy  = rem / 5 - 2;
        int dx  = rem % 5 - 2;
        int ny = cy + dy, nx = cx + dx;
        if (ny >= 0 && ny < GYD && nx >= 0 && nx < GXD) {
            int nvid = ((b * GZD + zz) * GYD + ny) * GXD + nx;
            float c = cnt[nvid];
            if (c > 0.0f) {
                occ  = true;
                ncn  = fmaxf(c, 1.0f);          // ref: sums / maximum(cnt,1)
                nxc  = sx[nvid] / ncn;
                nyc  = sy[nvid] / ncn;
                nrep = NPTS - rep[nvid];        // min point index of that voxel
            }
        }
    }

    // own voxel center broadcast from the (dx=0,dy=0,zz=cz) lane
    int lane_own = cz * 25 + 12;
    float cxf    = __shfl(nxc, lane_own);
    float cyf    = __shfl(nyc, lane_own);
    float cn_own = __shfl(ncn, lane_own);

    if (occ) {
        float ddx = cxf - nxc;
        float ddy = cyf - nyc;
        // separate roundings like ref (no FMA contraction)
        float sq = __fadd_rn(__fmul_rn(ddx, ddx), __fmul_rn(ddy, ddy));
        if (sqrtf(sq) < 0.6f && nrep != i)
            unite(parent, i, nrep);
    }

    if (lane == 0) {
        // float32 outputs: cluster_inds interleaved [b,c], valid, cpp
        out[2 * i]                = (float)b;
        out[2 * NPTS + i]         = 1.0f;       // cnt >= MIN_POINTS=1 always
        out[3 * NPTS + 3 * i + 0] = cxf;
        out[3 * NPTS + 3 * i + 1] = cyf;
        out[3 * NPTS + 3 * i + 2] = sz[vid] / cn_own;
    }
}

// Phase 3: labels = component root (== min point index == ref label).
// Separate dispatch => all unions device-visible; plain cached loads suffice
// (dispatch-start acquire), parent is 32KB -> L2-resident chases.
__global__ void k_final(const int* __restrict__ parent, float* __restrict__ out) {
    int i = blockIdx.x * blockDim.x + threadIdx.x;
    if (i >= NPTS) return;
    int r = parent[i];
    for (;;) {
        int rr = parent[r];
        if (rr == r) break;
        r = rr;
    }
    out[2 * i + 1] = (float)r;
}

extern "C" void kernel_launch(void* const* d_in, const int* in_sizes, int n_in,
                              void* d_out, int out_size, void* d_ws, size_t ws_size,
                              hipStream_t stream) {
    const float* pts  = (const float*)d_in[0];
    const int*   bidx = (const int*)d_in[1];
    float* out = (float*)d_out;

    char* w = (char*)d_ws;
    float* cnt    = (float*)(w + 0L * NVP * 4);
    float* sx     = (float*)(w + 1L * NVP * 4);
    float* sy     = (float*)(w + 2L * NVP * 4);
    float* sz     = (float*)(w + 3L * NVP * 4);
    int*   rep    = (int*)  (w + 4L * NVP * 4);
    int*   parent = (int*)  (w + 5L * NVP * 4);            // 8192 ints
    int*   pvid   = (int*)  (w + 5L * NVP * 4 + 32768);    // 8192 ints
    // ws use ~9 MB

    // Zero the five dense voxel arrays (cnt/sx/sy/sz/rep): ~1.3us of fill.
    hipMemsetAsync(w, 0, 5L * NVP * 4, stream);

    hipLaunchKernelGGL(k_accum, dim3(NPTS / 256), dim3(256), 0, stream,
                       pts, bidx, cnt, sx, sy, sz, rep, parent, pvid);
    hipLaunchKernelGGL(k_gather, dim3(GBLK), dim3(GTHR), 0, stream,
                       pvid, cnt, sx, sy, sz, rep, parent, out);
    hipLaunchKernelGGL(k_final, dim3(NPTS / 256), dim3(256), 0, stream,
                       parent, out);
}